// Round 6
// baseline (3031.852 us; speedup 1.0000x reference)
//
#include <hip/hip_runtime.h>
#include <hip/hip_bf16.h>
#include <math.h>

typedef unsigned long long u64;
typedef __hip_bfloat16 bf16;

#define L_ 2
#define B_ 32
#define N_ 225
#define M_ 1800
#define D_ 768
#define H_ 256
#define MID_ 128
#define EPS_ 1e-5f

struct __align__(8) us4 { unsigned short x, y, z, w; };

__device__ __forceinline__ float bf2f(unsigned short u) {
  return __uint_as_float(((unsigned)u) << 16);
}

__device__ __forceinline__ u64 enc_key(float v, int idx) {
  unsigned u = __float_as_uint(v);
  u = (u & 0x80000000u) ? ~u : (u | 0x80000000u);
  return ((u64)u << 32) | (u64)(0x7FFFFFFFu - (unsigned)idx);
}

// ---------------- norms ----------------
__global__ __launch_bounds__(256) void k_norms(const float* __restrict__ q,
                                               const float* __restrict__ p,
                                               float* __restrict__ qinv,
                                               float* __restrict__ pinv) {
  int row = blockIdx.x;
  const float* src;
  float* dst;
  if (row < B_ * N_) {
    src = q + (size_t)row * D_;
    dst = qinv + row;
  } else {
    int r = row - B_ * N_;
    src = p + (size_t)r * D_;
    dst = pinv + r;
  }
  float s = 0.f;
  for (int i = threadIdx.x; i < D_; i += 256) {
    float v = src[i];
    s = fmaf(v, v, s);
  }
  __shared__ float red[256];
  red[threadIdx.x] = s;
  __syncthreads();
  for (int off = 128; off > 0; off >>= 1) {
    if (threadIdx.x < off) red[threadIdx.x] += red[threadIdx.x + off];
    __syncthreads();
  }
  if (threadIdx.x == 0) {
    float n = sqrtf(red[0]);
    n = fmaxf(n, 1e-12f);
    *dst = 1.0f / n;
  }
}

__global__ void k_init(u64* __restrict__ keys) {
  int i = blockIdx.x * 256 + threadIdx.x;
  if (i < B_ * N_) keys[i] = 0ULL;
}

// ---------------- cosine sim + argmax (normalize-first, f32) ----------------
__global__ __launch_bounds__(256) void k_sim(const float* __restrict__ q,
                                             const float* __restrict__ p,
                                             const float* __restrict__ qinv,
                                             const float* __restrict__ pinv,
                                             u64* __restrict__ keys) {
  const int b = blockIdx.z;
  const int n0 = blockIdx.x * 64;
  const int m0 = blockIdx.y * 64;
  __shared__ float As[32][68];
  __shared__ float Bs[32][68];
  __shared__ u64 red[64][17];
  float acc[4][4] = {};
  const int t = threadIdx.x;
  const int tn = t >> 4, tm = t & 15;
  const int lr = t >> 3;
  const int lc = (t & 7) << 2;
  const float* qb = q + (size_t)b * N_ * D_;
  const float* pb = p + (size_t)b * M_ * D_;
  float qs[2], ps[2];
#pragma unroll
  for (int rep = 0; rep < 2; ++rep) {
    int n = n0 + lr + rep * 32;
    qs[rep] = (n < N_) ? qinv[(size_t)b * N_ + n] : 0.f;
    int m = m0 + lr + rep * 32;
    ps[rep] = (m < M_) ? pinv[(size_t)b * M_ + m] : 0.f;
  }

  for (int k0 = 0; k0 < D_; k0 += 32) {
#pragma unroll
    for (int rep = 0; rep < 2; ++rep) {
      int r = lr + rep * 32;
      float4 av = make_float4(0.f, 0.f, 0.f, 0.f);
      int n = n0 + r;
      if (n < N_) av = *(const float4*)(qb + (size_t)n * D_ + k0 + lc);
      As[lc + 0][r] = av.x * qs[rep]; As[lc + 1][r] = av.y * qs[rep];
      As[lc + 2][r] = av.z * qs[rep]; As[lc + 3][r] = av.w * qs[rep];
      float4 bv = make_float4(0.f, 0.f, 0.f, 0.f);
      int m = m0 + r;
      if (m < M_) bv = *(const float4*)(pb + (size_t)m * D_ + k0 + lc);
      Bs[lc + 0][r] = bv.x * ps[rep]; Bs[lc + 1][r] = bv.y * ps[rep];
      Bs[lc + 2][r] = bv.z * ps[rep]; Bs[lc + 3][r] = bv.w * ps[rep];
    }
    __syncthreads();
#pragma unroll
    for (int kk = 0; kk < 32; ++kk) {
      const float4 a = *(const float4*)&As[kk][tn << 2];
      const float4 w = *(const float4*)&Bs[kk][tm << 2];
      acc[0][0] = fmaf(a.x, w.x, acc[0][0]);
      acc[0][1] = fmaf(a.x, w.y, acc[0][1]);
      acc[0][2] = fmaf(a.x, w.z, acc[0][2]);
      acc[0][3] = fmaf(a.x, w.w, acc[0][3]);
      acc[1][0] = fmaf(a.y, w.x, acc[1][0]);
      acc[1][1] = fmaf(a.y, w.y, acc[1][1]);
      acc[1][2] = fmaf(a.y, w.z, acc[1][2]);
      acc[1][3] = fmaf(a.y, w.w, acc[1][3]);
      acc[2][0] = fmaf(a.z, w.x, acc[2][0]);
      acc[2][1] = fmaf(a.z, w.y, acc[2][1]);
      acc[2][2] = fmaf(a.z, w.z, acc[2][2]);
      acc[2][3] = fmaf(a.z, w.w, acc[2][3]);
      acc[3][0] = fmaf(a.w, w.x, acc[3][0]);
      acc[3][1] = fmaf(a.w, w.y, acc[3][1]);
      acc[3][2] = fmaf(a.w, w.z, acc[3][2]);
      acc[3][3] = fmaf(a.w, w.w, acc[3][3]);
    }
    __syncthreads();
  }
  const int mbase = m0 + (tm << 2);
#pragma unroll
  for (int i = 0; i < 4; ++i) {
    u64 bk = 0ULL;
#pragma unroll
    for (int j = 0; j < 4; ++j) {
      int m = mbase + j;
      if (m < M_) {
        u64 k = enc_key(acc[i][j], m);
        if (k > bk) bk = k;
      }
    }
    red[(tn << 2) + i][tm] = bk;
  }
  __syncthreads();
  if (t < 64) {
    u64 bk = 0ULL;
#pragma unroll
    for (int j = 0; j < 16; ++j) {
      u64 k = red[t][j];
      if (k > bk) bk = k;
    }
    int n = n0 + t;
    if (n < N_) atomicMax(&keys[(size_t)b * N_ + n], bk);
  }
}

__global__ void k_decode(const u64* __restrict__ keys, float* __restrict__ residual,
                         int* __restrict__ idxbuf, float* __restrict__ out_res,
                         float* __restrict__ out_idx) {
  int i = blockIdx.x * 256 + threadIdx.x;
  if (i >= B_ * N_) return;
  u64 k = keys[i];
  unsigned u = (unsigned)(k >> 32);
  unsigned bits = (u & 0x80000000u) ? (u & 0x7FFFFFFFu) : ~u;
  float v = __uint_as_float(bits);
  int idx = (int)(0x7FFFFFFFu - (unsigned)(k & 0xFFFFFFFFu));
  if (idx < 0) idx = 0;
  if (idx >= M_) idx = M_ - 1;
  float r = 1.0f - v;
  if (r != r) r = 0.f;
  residual[i] = r;
  idxbuf[i] = idx;
  out_res[i] = r;
  out_idx[i] = (float)idx;
}

// ---------------- ctx -> BN -> cmap (bf16 scratch, [B*N][D]) ----------------
__global__ __launch_bounds__(256) void k_cmap(const float* __restrict__ q,
    const float* __restrict__ p, const int* __restrict__ idxbuf,
    const float* __restrict__ g, const float* __restrict__ bb,
    const float* __restrict__ bm, const float* __restrict__ bv,
    bf16* __restrict__ cmap) {
  int bn = blockIdx.x;
  int b = bn / N_;
  int id = idxbuf[bn];
  if (id < 0) id = 0;
  if (id >= M_) id = M_ - 1;
  const float* qr = q + (size_t)bn * D_;
  const float* pr = p + ((size_t)b * M_ + id) * D_;
  for (int d = threadIdx.x; d < D_; d += 256) {
    float qv = qr[d], pv = pr[d];
    float c = qv + fabsf(qv - pv);
    float val = (c - bm[d]) * (g[d] * rsqrtf(bv[d] + EPS_)) + bb[d];
    cmap[(size_t)bn * D_ + d] = __float2bfloat16(val);
  }
}

// ---------------- weight reshapes to bf16 [k][cout] ----------------
__global__ void k_prepw(const float* __restrict__ lc1, const float* __restrict__ lt1,
                        const float* __restrict__ lc2, const float* __restrict__ lt2,
                        bf16* __restrict__ wt1, bf16* __restrict__ wtT1,
                        bf16* __restrict__ wt2, bf16* __restrict__ wtT2) {
  int i = blockIdx.x * 256 + threadIdx.x;
  const int n1 = 9 * D_ * H_;      // 1769472
  const int n2 = 4 * H_ * H_;      // 262144
  const int n3 = 9 * H_ * MID_;    // 294912
  const int n4 = 4 * MID_ * MID_;  // 65536
  if (i < n1) {
    int co = i & 255;
    int rest = i >> 8;
    int d = rest % D_;
    int tap = rest / D_;
    wt1[i] = __float2bfloat16(lc1[((size_t)co * D_ + d) * 9 + tap]);
  } else if (i < n1 + n2) {
    int j = i - n1;
    int co = j & 255;
    int r2 = j >> 8;
    int ci = r2 & 255;
    int ij = r2 >> 8;
    wtT1[j] = __float2bfloat16(lt1[((size_t)ci * H_ + co) * 4 + ij]);
  } else if (i < n1 + n2 + n3) {
    int j = i - n1 - n2;
    int co = j & 127;
    int r2 = j >> 7;
    int ci = r2 & 255;
    int tap = r2 >> 8;
    wt2[j] = __float2bfloat16(lc2[((size_t)co * H_ + ci) * 9 + tap]);
  } else if (i < n1 + n2 + n3 + n4) {
    int j = i - n1 - n2 - n3;
    int co = j & 127;
    int r2 = j >> 7;
    int ci = r2 & 127;
    int ij = r2 >> 7;
    wtT2[j] = __float2bfloat16(lt2[((size_t)ci * MID_ + co) * 4 + ij]);
  }
}

// ---------------- conv3x3 (+BN+ReLU), bf16 I/O, f32 LDS/acc ----------------
template <int SHW, int CIN, int COUT>
__global__ __launch_bounds__(256) void k_conv3x3(const bf16* __restrict__ in,
    const bf16* __restrict__ wt, const float* __restrict__ bg,
    const float* __restrict__ bbeta, const float* __restrict__ bm,
    const float* __restrict__ bv, bf16* __restrict__ outp) {
  constexpr int S = SHW * SHW;
  const int b = blockIdx.z;
  const int s0 = blockIdx.x * 64;
  const int c0 = blockIdx.y * 64;
  __shared__ float As[32][68];
  __shared__ float Bs[32][68];
  float acc[4][4] = {};
  const int t = threadIdx.x;
  const int tn = t >> 4, tm = t & 15;
  const int lr = t >> 3;
  const int lc = (t & 7) << 2;
  const int lkb = t >> 4;
  const int lcb = (t & 15) << 2;
  const bf16* inb = in + (size_t)b * S * CIN;
  for (int tap = 0; tap < 9; ++tap) {
    const int dy = tap / 3 - 1, dx = tap % 3 - 1;
    for (int c00 = 0; c00 < CIN; c00 += 32) {
      const int k0 = tap * CIN + c00;
#pragma unroll
      for (int rep = 0; rep < 2; ++rep) {
        int r = lr + rep * 32;
        int s = s0 + r;
        us4 av = {0, 0, 0, 0};
        if (s < S) {
          int sy = s / SHW + dy, sx = s % SHW + dx;
          if (sy >= 0 && sy < SHW && sx >= 0 && sx < SHW)
            av = *(const us4*)(inb + (size_t)(sy * SHW + sx) * CIN + c00 + lc);
        }
        As[lc + 0][r] = bf2f(av.x); As[lc + 1][r] = bf2f(av.y);
        As[lc + 2][r] = bf2f(av.z); As[lc + 3][r] = bf2f(av.w);
        int kk = lkb + rep * 16;
        us4 wv = *(const us4*)(wt + (size_t)(k0 + kk) * COUT + c0 + lcb);
        Bs[kk][lcb + 0] = bf2f(wv.x); Bs[kk][lcb + 1] = bf2f(wv.y);
        Bs[kk][lcb + 2] = bf2f(wv.z); Bs[kk][lcb + 3] = bf2f(wv.w);
      }
      __syncthreads();
#pragma unroll
      for (int kk = 0; kk < 32; ++kk) {
        const float4 a = *(const float4*)&As[kk][tn << 2];
        const float4 w = *(const float4*)&Bs[kk][tm << 2];
        acc[0][0] = fmaf(a.x, w.x, acc[0][0]);
        acc[0][1] = fmaf(a.x, w.y, acc[0][1]);
        acc[0][2] = fmaf(a.x, w.z, acc[0][2]);
        acc[0][3] = fmaf(a.x, w.w, acc[0][3]);
        acc[1][0] = fmaf(a.y, w.x, acc[1][0]);
        acc[1][1] = fmaf(a.y, w.y, acc[1][1]);
        acc[1][2] = fmaf(a.y, w.z, acc[1][2]);
        acc[1][3] = fmaf(a.y, w.w, acc[1][3]);
        acc[2][0] = fmaf(a.z, w.x, acc[2][0]);
        acc[2][1] = fmaf(a.z, w.y, acc[2][1]);
        acc[2][2] = fmaf(a.z, w.z, acc[2][2]);
        acc[2][3] = fmaf(a.z, w.w, acc[2][3]);
        acc[3][0] = fmaf(a.w, w.x, acc[3][0]);
        acc[3][1] = fmaf(a.w, w.y, acc[3][1]);
        acc[3][2] = fmaf(a.w, w.z, acc[3][2]);
        acc[3][3] = fmaf(a.w, w.w, acc[3][3]);
      }
      __syncthreads();
    }
  }
  float sc[4], sh[4];
#pragma unroll
  for (int j = 0; j < 4; ++j) {
    int c = c0 + (tm << 2) + j;
    float s = bg[c] * rsqrtf(bv[c] + EPS_);
    sc[j] = s;
    sh[j] = bbeta[c] - bm[c] * s;
  }
#pragma unroll
  for (int i = 0; i < 4; ++i) {
    int s = s0 + (tn << 2) + i;
    if (s < S) {
      bf16* o = outp + ((size_t)b * S + s) * COUT + c0 + (tm << 2);
      o[0] = __float2bfloat16(fmaxf(fmaf(acc[i][0], sc[0], sh[0]), 0.f));
      o[1] = __float2bfloat16(fmaxf(fmaf(acc[i][1], sc[1], sh[1]), 0.f));
      o[2] = __float2bfloat16(fmaxf(fmaf(acc[i][2], sc[2], sh[2]), 0.f));
      o[3] = __float2bfloat16(fmaxf(fmaf(acc[i][3], sc[3], sh[3]), 0.f));
    }
  }
}

// ---------------- ConvTranspose2d k=2 s=2 (+bias), bf16 I/O ----------------
template <int SHW, int C>
__global__ __launch_bounds__(256) void k_convT(const bf16* __restrict__ in,
    const bf16* __restrict__ wt, const float* __restrict__ bias,
    bf16* __restrict__ outp) {
  constexpr int S = SHW * SHW;
  const int b = blockIdx.z;
  const int ij = blockIdx.y & 3;
  const int c0 = (blockIdx.y >> 2) * 64;
  const int s0 = blockIdx.x * 64;
  __shared__ float As[32][68];
  __shared__ float Bs[32][68];
  float acc[4][4] = {};
  const int t = threadIdx.x;
  const int tn = t >> 4, tm = t & 15;
  const int lr = t >> 3;
  const int lc = (t & 7) << 2;
  const int lkb = t >> 4;
  const int lcb = (t & 15) << 2;
  const bf16* inb = in + (size_t)b * S * C;
  const bf16* wij = wt + (size_t)ij * C * C;
  for (int k0 = 0; k0 < C; k0 += 32) {
#pragma unroll
    for (int rep = 0; rep < 2; ++rep) {
      int r = lr + rep * 32;
      int s = s0 + r;
      us4 av = {0, 0, 0, 0};
      if (s < S) av = *(const us4*)(inb + (size_t)s * C + k0 + lc);
      As[lc + 0][r] = bf2f(av.x); As[lc + 1][r] = bf2f(av.y);
      As[lc + 2][r] = bf2f(av.z); As[lc + 3][r] = bf2f(av.w);
      int kk = lkb + rep * 16;
      us4 wv = *(const us4*)(wij + (size_t)(k0 + kk) * C + c0 + lcb);
      Bs[kk][lcb + 0] = bf2f(wv.x); Bs[kk][lcb + 1] = bf2f(wv.y);
      Bs[kk][lcb + 2] = bf2f(wv.z); Bs[kk][lcb + 3] = bf2f(wv.w);
    }
    __syncthreads();
#pragma unroll
    for (int kk = 0; kk < 32; ++kk) {
      const float4 a = *(const float4*)&As[kk][tn << 2];
      const float4 w = *(const float4*)&Bs[kk][tm << 2];
      acc[0][0] = fmaf(a.x, w.x, acc[0][0]);
      acc[0][1] = fmaf(a.x, w.y, acc[0][1]);
      acc[0][2] = fmaf(a.x, w.z, acc[0][2]);
      acc[0][3] = fmaf(a.x, w.w, acc[0][3]);
      acc[1][0] = fmaf(a.y, w.x, acc[1][0]);
      acc[1][1] = fmaf(a.y, w.y, acc[1][1]);
      acc[1][2] = fmaf(a.y, w.z, acc[1][2]);
      acc[1][3] = fmaf(a.y, w.w, acc[1][3]);
      acc[2][0] = fmaf(a.z, w.x, acc[2][0]);
      acc[2][1] = fmaf(a.z, w.y, acc[2][1]);
      acc[2][2] = fmaf(a.z, w.z, acc[2][2]);
      acc[2][3] = fmaf(a.z, w.w, acc[2][3]);
      acc[3][0] = fmaf(a.w, w.x, acc[3][0]);
      acc[3][1] = fmaf(a.w, w.y, acc[3][1]);
      acc[3][2] = fmaf(a.w, w.z, acc[3][2]);
      acc[3][3] = fmaf(a.w, w.w, acc[3][3]);
    }
    __syncthreads();
  }
  float bj[4];
#pragma unroll
  for (int j = 0; j < 4; ++j) bj[j] = bias[c0 + (tm << 2) + j];
#pragma unroll
  for (int i = 0; i < 4; ++i) {
    int s = s0 + (tn << 2) + i;
    if (s < S) {
      int oy = 2 * (s / SHW) + (ij >> 1);
      int ox = 2 * (s % SHW) + (ij & 1);
      bf16* o = outp + ((size_t)b * 4 * S + (size_t)oy * (2 * SHW) + ox) * C + c0 + (tm << 2);
      o[0] = __float2bfloat16(acc[i][0] + bj[0]);
      o[1] = __float2bfloat16(acc[i][1] + bj[1]);
      o[2] = __float2bfloat16(acc[i][2] + bj[2]);
      o[3] = __float2bfloat16(acc[i][3] + bj[3]);
    }
  }
}

// ---------------- convT2 (30->60) fused with 1x1 conv -> atomicAdd l2c ----------------
__global__ __launch_bounds__(256) void k_convT_fuse(const bf16* __restrict__ in,
    const bf16* __restrict__ wt, const float* __restrict__ w3,
    float* __restrict__ l2c) {
  constexpr int SHW = 30, C = 128, S = SHW * SHW;
  const int b = blockIdx.z;
  const int ij = blockIdx.y & 3;
  const int c0 = (blockIdx.y >> 2) * 64;
  const int s0 = blockIdx.x * 64;
  __shared__ float As[32][68];
  __shared__ float Bs[32][68];
  __shared__ float r0[64][17];
  __shared__ float r1[64][17];
  float acc[4][4] = {};
  const int t = threadIdx.x;
  const int tn = t >> 4, tm = t & 15;
  const int lr = t >> 3;
  const int lc = (t & 7) << 2;
  const int lkb = t >> 4;
  const int lcb = (t & 15) << 2;
  const bf16* inb = in + (size_t)b * S * C;
  const bf16* wij = wt + (size_t)ij * C * C;
  for (int k0 = 0; k0 < C; k0 += 32) {
#pragma unroll
    for (int rep = 0; rep < 2; ++rep) {
      int r = lr + rep * 32;
      int s = s0 + r;
      us4 av = {0, 0, 0, 0};
      if (s < S) av = *(const us4*)(inb + (size_t)s * C + k0 + lc);
      As[lc + 0][r] = bf2f(av.x); As[lc + 1][r] = bf2f(av.y);
      As[lc + 2][r] = bf2f(av.z); As[lc + 3][r] = bf2f(av.w);
      int kk = lkb + rep * 16;
      us4 wv = *(const us4*)(wij + (size_t)(k0 + kk) * C + c0 + lcb);
      Bs[kk][lcb + 0] = bf2f(wv.x); Bs[kk][lcb + 1] = bf2f(wv.y);
      Bs[kk][lcb + 2] = bf2f(wv.z); Bs[kk][lcb + 3] = bf2f(wv.w);
    }
    __syncthreads();
#pragma unroll
    for (int kk = 0; kk < 32; ++kk) {
      const float4 a = *(const float4*)&As[kk][tn << 2];
      const float4 w = *(const float4*)&Bs[kk][tm << 2];
      acc[0][0] = fmaf(a.x, w.x, acc[0][0]);
      acc[0][1] = fmaf(a.x, w.y, acc[0][1]);
      acc[0][2] = fmaf(a.x, w.z, acc[0][2]);
      acc[0][3] = fmaf(a.x, w.w, acc[0][3]);
      acc[1][0] = fmaf(a.y, w.x, acc[1][0]);
      acc[1][1] = fmaf(a.y, w.y, acc[1][1]);
      acc[1][2] = fmaf(a.y, w.z, acc[1][2]);
      acc[1][3] = fmaf(a.y, w.w, acc[1][3]);
      acc[2][0] = fmaf(a.z, w.x, acc[2][0]);
      acc[2][1] = fmaf(a.z, w.y, acc[2][1]);
      acc[2][2] = fmaf(a.z, w.z, acc[2][2]);
      acc[2][3] = fmaf(a.z, w.w, acc[2][3]);
      acc[3][0] = fmaf(a.w, w.x, acc[3][0]);
      acc[3][1] = fmaf(a.w, w.y, acc[3][1]);
      acc[3][2] = fmaf(a.w, w.z, acc[3][2]);
      acc[3][3] = fmaf(a.w, w.w, acc[3][3]);
    }
    __syncthreads();
  }
  float w0j[4], w1j[4];
#pragma unroll
  for (int j = 0; j < 4; ++j) {
    int c = c0 + (tm << 2) + j;
    w0j[j] = w3[c];
    w1j[j] = w3[MID_ + c];
  }
#pragma unroll
  for (int i = 0; i < 4; ++i) {
    float a0 = 0.f, a1 = 0.f;
#pragma unroll
    for (int j = 0; j < 4; ++j) {
      a0 = fmaf(acc[i][j], w0j[j], a0);
      a1 = fmaf(acc[i][j], w1j[j], a1);
    }
    r0[(tn << 2) + i][tm] = a0;
    r1[(tn << 2) + i][tm] = a1;
  }
  __syncthreads();
  if (t < 64) {
    int s = s0 + t;
    if (s < S) {
      float v0 = 0.f, v1 = 0.f;
#pragma unroll
      for (int g = 0; g < 16; ++g) { v0 += r0[t][g]; v1 += r1[t][g]; }
      int oy = 2 * (s / SHW) + (ij >> 1);
      int ox = 2 * (s % SHW) + (ij & 1);
      int opix = oy * 60 + ox;
      atomicAdd(&l2c[(size_t)b * 7200 + opix], v0);
      atomicAdd(&l2c[(size_t)b * 7200 + 3600 + opix], v1);
    }
  }
}

// ---------------- l2c init: b3 + lt2_b folded through 1x1 ----------------
__global__ void k_l2cinit(const float* __restrict__ lt2b, const float* __restrict__ w3,
                          const float* __restrict__ b3, float* __restrict__ l2c) {
  __shared__ float ini[2];
  int t = threadIdx.x;
  if (t < 2) {
    float s = b3[t];
    for (int ci = 0; ci < MID_; ++ci) s = fmaf(lt2b[ci], w3[t * MID_ + ci], s);
    ini[t] = s;
  }
  __syncthreads();
  int i = blockIdx.x * 256 + t;
  if (i < 7200) l2c[(size_t)blockIdx.y * 7200 + i] = ini[i / 3600];
}

// ---------------- patch head: exact resize(resize(60->240)->15) + evidence ----------------
__global__ __launch_bounds__(256) void k_patch(const float* __restrict__ l2c,
    const float* __restrict__ residual, float* __restrict__ out_ev,
    float* __restrict__ out_pl) {
  const int b = blockIdx.x;
  __shared__ float sm0[3600];
  __shared__ float sm1[3600];
  for (int i = threadIdx.x; i < 3600; i += 256) {
    sm0[i] = l2c[(size_t)b * 7200 + i];
    sm1[i] = l2c[(size_t)b * 7200 + 3600 + i];
  }
  __syncthreads();
  const int t = threadIdx.x;
  if (t >= 225) return;
  const int py = t / 15, px = t % 15;
  const float cy = 16.f * py + 7.5f;
  const float cx = 16.f * px + 7.5f;
  const int ky_lo = max(0, 16 * py - 8), ky_hi = min(239, 16 * py + 23);
  const int kx_lo = max(0, 16 * px - 8), kx_hi = min(239, 16 * px + 23);
  float acc0 = 0.f, acc1 = 0.f, wsum = 0.f;
  for (int ky = ky_lo; ky <= ky_hi; ++ky) {
    float wy = 1.f - fabsf((float)ky - cy) * 0.0625f;
    float c60y = 0.25f * ky - 0.375f;
    int jy = (int)floorf(c60y);
    float fy = c60y - (float)jy;
    int jy0 = max(jy, 0), jy1 = min(jy + 1, 59);
    for (int kx = kx_lo; kx <= kx_hi; ++kx) {
      float wx = 1.f - fabsf((float)kx - cx) * 0.0625f;
      float w = wy * wx;
      float c60x = 0.25f * kx - 0.375f;
      int jx = (int)floorf(c60x);
      float fx = c60x - (float)jx;
      int jx0 = max(jx, 0), jx1 = min(jx + 1, 59);
      float v0 = (1.f - fy) * ((1.f - fx) * sm0[jy0 * 60 + jx0] + fx * sm0[jy0 * 60 + jx1])
               + fy * ((1.f - fx) * sm0[jy1 * 60 + jx0] + fx * sm0[jy1 * 60 + jx1]);
      float v1 = (1.f - fy) * ((1.f - fx) * sm1[jy0 * 60 + jx0] + fx * sm1[jy0 * 60 + jx1])
               + fy * ((1.f - fx) * sm1[jy1 * 60 + jx0] + fx * sm1[jy1 * 60 + jx1]);
      acc0 = fmaf(w, v0, acc0);
      acc1 = fmaf(w, v1, acc1);
      wsum += w;
    }
  }
  float p0 = acc0 / wsum, p1 = acc1 / wsum;
  float logit = p1 - p0;
  float score1 = 1.0f / (1.0f + expf(p0 - p1));
  float ev = 0.5f * residual[b * N_ + t] + 0.5f * score1;
  out_pl[b * N_ + t] = logit;
  out_ev[b * N_ + t] = ev;
}

// ---------------- upsample 60->240 bilinear: write local2c AND softmax (f32) ----------------
__global__ __launch_bounds__(256) void k_up(const float* __restrict__ l2c,
                                            float* __restrict__ out_l2c,
                                            float* __restrict__ out_ls) {
  const int b = blockIdx.y;
  const int pix = blockIdx.x * 256 + threadIdx.x;  // 57600
  const int y = pix / 240, x = pix % 240;
  float sy = 0.25f * y - 0.375f;
  int ky = (int)floorf(sy);
  float fy = sy - (float)ky;
  float sx = 0.25f * x - 0.375f;
  int kx = (int)floorf(sx);
  float fx = sx - (float)kx;
  int ky0 = max(ky, 0), ky1 = min(ky + 1, 59);
  int kx0 = max(kx, 0), kx1 = min(kx + 1, 59);
  float v[2];
#pragma unroll
  for (int c = 0; c < 2; ++c) {
    const float* base = l2c + ((size_t)b * 2 + c) * 3600;
    float top = (1.f - fx) * base[ky0 * 60 + kx0] + fx * base[ky0 * 60 + kx1];
    float bot = (1.f - fx) * base[ky1 * 60 + kx0] + fx * base[ky1 * 60 + kx1];
    v[c] = (1.f - fy) * top + fy * bot;
  }
  float s1 = 1.f / (1.f + expf(v[0] - v[1]));
  float s0 = 1.f / (1.f + expf(v[1] - v[0]));
  size_t o0 = ((size_t)b * 2 + 0) * 57600 + pix;
  size_t o1 = ((size_t)b * 2 + 1) * 57600 + pix;
  out_l2c[o0] = v[0];
  out_l2c[o1] = v[1];
  out_ls[o0] = s0;
  out_ls[o1] = s1;
}

// ---------------- fusion stats (strided read from cmap [B*N][D]) ----------------
__global__ __launch_bounds__(256) void k_fusion(const bf16* __restrict__ cmap,
                                                float* __restrict__ gfeat) {
  int wid = ((blockIdx.x * 256 + threadIdx.x) >> 6);
  int lane = threadIdx.x & 63;
  if (wid >= B_ * D_) return;
  int b = wid / D_, d = wid % D_;
  const bf16* base = cmap + (size_t)b * N_ * D_ + d;
  float v[4];
  bool alive[4];
  float sum = 0.f;
#pragma unroll
  for (int r = 0; r < 4; ++r) {
    int n = lane + r * 64;
    bool ok = (n < N_);
    v[r] = ok ? __bfloat162float(base[(size_t)n * D_]) : -INFINITY;
    alive[r] = ok;
    if (ok) sum += v[r];
  }
  for (int o = 32; o > 0; o >>= 1) sum += __shfl_xor(sum, o);
  float topsum = 0.f;
  for (int it = 0; it < 10; ++it) {
    float lm = -INFINITY;
    int ls = -1;
#pragma unroll
    for (int r = 0; r < 4; ++r)
      if (alive[r] && v[r] > lm) { lm = v[r]; ls = r; }
    float wm = lm;
    for (int o = 32; o > 0; o >>= 1) wm = fmaxf(wm, __shfl_xor(wm, o));
    topsum += wm;
    u64 ball = __ballot(lm == wm);
    int owner = __ffsll((long long)ball) - 1;
    if (lane == owner && ls >= 0) alive[ls] = false;
  }
  if (lane == 0) gfeat[wid] = 0.5f * (sum / 225.0f + topsum * 0.1f);
}

// ---------------- fused FC head ----------------
__global__ __launch_bounds__(256) void k_fc(const float* __restrict__ gfeat,
    const float* __restrict__ g1w, const float* __restrict__ bg1,
    const float* __restrict__ bb1, const float* __restrict__ bm1,
    const float* __restrict__ bv1, const float* __restrict__ g2w,
    const float* __restrict__ bg2, const float* __restrict__ bb2,
    const float* __restrict__ bm2, const float* __restrict__ bv2,
    const float* __restrict__ g3w, float* __restrict__ out_gl,
    float* __restrict__ out_g2c) {
  __shared__ float gf[D_];
  __shared__ float h1s[H_];
  __shared__ float h2s[MID_];
  __shared__ float g2cs[2];
  const int b = blockIdx.x;
  const int t = threadIdx.x;
  for (int i = t; i < D_; i += 256) gf[i] = gfeat[b * D_ + i];
  __syncthreads();
  {
    float a = 0.f;
    const float* w = g1w + (size_t)t * D_;
    for (int d = 0; d < D_; ++d) a = fmaf(gf[d], w[d], a);
    float s = bg1[t] * rsqrtf(bv1[t] + EPS_);
    h1s[t] = fmaxf((a - bm1[t]) * s + bb1[t], 0.f);
  }
  __syncthreads();
  if (t < MID_) {
    float a = 0.f;
    const float* w = g2w + (size_t)t * H_;
    for (int k = 0; k < H_; ++k) a = fmaf(h1s[k], w[k], a);
    float s = bg2[t] * rsqrtf(bv2[t] + EPS_);
    h2s[t] = fmaxf((a - bm2[t]) * s + bb2[t], 0.f);
  }
  __syncthreads();
  if (t < 2) {
    float a = 0.f;
    const float* w = g3w + (size_t)t * MID_;
    for (int k = 0; k < MID_; ++k) a = fmaf(h2s[k], w[k], a);
    g2cs[t] = a;
    out_g2c[b * 2 + t] = a;
  }
  __syncthreads();
  if (t == 0) out_gl[b] = g2cs[1] - g2cs[0];
}

// ================= host =================
extern "C" void kernel_launch(void* const* d_in, const int* in_sizes, int n_in,
                              void* d_out, int out_size, void* d_ws, size_t ws_size,
                              hipStream_t stream) {
  (void)in_sizes; (void)n_in; (void)out_size; (void)ws_size;
  const float* query = (const float*)d_in[0];
  const float* prompt = (const float*)d_in[1];
  const float* bns_g = (const float*)d_in[2];
  const float* bns_b = (const float*)d_in[3];
  const float* bns_m = (const float*)d_in[4];
  const float* bns_v = (const float*)d_in[5];
  const float* lc1_w = (const float*)d_in[6];
  const float* lbn1_g = (const float*)d_in[7];
  const float* lbn1_b = (const float*)d_in[8];
  const float* lbn1_m = (const float*)d_in[9];
  const float* lbn1_v = (const float*)d_in[10];
  const float* lt1_w = (const float*)d_in[11];
  const float* lt1_b = (const float*)d_in[12];
  const float* lc2_w = (const float*)d_in[13];
  const float* lbn2_g = (const float*)d_in[14];
  const float* lbn2_b = (const float*)d_in[15];
  const float* lbn2_m = (const float*)d_in[16];
  const float* lbn2_v = (const float*)d_in[17];
  const float* lt2_w = (const float*)d_in[18];
  const float* lt2_b = (const float*)d_in[19];
  const float* lc3_w = (const float*)d_in[20];
  const float* lc3_b = (const float*)d_in[21];
  const float* g1_w = (const float*)d_in[22];
  const float* gbn1_g = (const float*)d_in[23];
  const float* gbn1_b = (const float*)d_in[24];
  const float* gbn1_m = (const float*)d_in[25];
  const float* gbn1_v = (const float*)d_in[26];
  const float* g2_w = (const float*)d_in[27];
  const float* gbn2_g = (const float*)d_in[28];
  const float* gbn2_b = (const float*)d_in[29];
  const float* gbn2_m = (const float*)d_in[30];
  const float* gbn2_v = (const float*)d_in[31];
  const float* g3_w = (const float*)d_in[32];

  float* ob = (float*)d_out;       // OUTPUT IS FLOAT32 (proven by R1-R5 byte fingerprints)
  char* ob_c = (char*)d_out;
  char* ws = (char*)d_ws;
  // --- small workspace (~6.8 MB total) ---
  u64* keys = (u64*)(ws + 0);                    // 57,600 B
  float* qinv = (float*)(ws + 57600);            // 28,800
  float* pinv = (float*)(ws + 86400);            // 230,400
  float* residual = (float*)(ws + 316800);       // L x 7200 f32 = 57,600
  int* idxbuf = (int*)(ws + 374400);             // 28,800
  float* gfeat = (float*)(ws + 403200);          // 98,304
  float* l2c = (float*)(ws + 501504);            // L x 230,400 f32 = 1,843,200
  bf16* wt1 = (bf16*)(ws + 2344704);             // 3,538,944
  bf16* wtT1 = (bf16*)(ws + 5883648);            // 524,288
  bf16* wt2 = (bf16*)(ws + 6407936);             // 589,824
  bf16* wtT2 = (bf16*)(ws + 6997760);            // 131,072 -> end 7,128,832

  // output offsets in f32 elements (return order: ev, pl, gl, g2c, l2c, ls, res, idx)
  const size_t OFF_EV = 0;            // [L,B,225]
  const size_t OFF_PL = 14400;        // [L,B,225]
  const size_t OFF_GL = 28800;        // [L,B]
  const size_t OFF_G2C = 28864;       // [L,B,2]
  const size_t OFF_L2C = 28992;       // [L,B,2,240,240]
  const size_t OFF_LS = 7401792;      // [L,B,2,240,240]
  const size_t OFF_RES = 14774592;    // [L,B,225]
  const size_t OFF_IDX = 14788992;    // [L,B,225]

  // --- bf16 conv scratch packed into the BYTE range of the l2c/ls chunks
  //     (bytes [115968, 59098368)); fully overwritten by k_up in phase B ---
  bf16* cmap = (bf16*)(ob_c + 115968);     // 11,059,200 B -> 11,175,168
  bf16* x1 = (bf16*)(ob_c + 11175168);     //  3,686,400 B -> 14,861,568
  bf16* y1 = (bf16*)(ob_c + 14861568);     // 14,745,600 B -> 29,607,168
  bf16* x2 = (bf16*)(ob_c + 29607168);     //  7,372,800 B -> 36,979,968 (< 59,098,368 ok)

  // ---------- phase A: sim/argmax, heads, convs -> l2c in ws (per layer) ----------
  for (int l = 0; l < L_; ++l) {
    const float* q = query + (size_t)l * B_ * N_ * D_;
    const float* p = prompt + (size_t)l * B_ * M_ * D_;
    float* out_gl = ob + OFF_GL + (size_t)l * B_;
    float* out_g2c = ob + OFF_G2C + (size_t)l * B_ * 2;
    float* out_res = ob + OFF_RES + (size_t)l * B_ * N_;
    float* out_idx = ob + OFF_IDX + (size_t)l * B_ * N_;
    float* res_l = residual + (size_t)l * B_ * N_;
    float* l2c_l = l2c + (size_t)l * B_ * 7200;

    k_norms<<<dim3(B_ * (N_ + M_)), dim3(256), 0, stream>>>(q, p, qinv, pinv);
    k_init<<<dim3(29), dim3(256), 0, stream>>>(keys);
    k_sim<<<dim3(4, 29, B_), dim3(256), 0, stream>>>(q, p, qinv, pinv, keys);
    k_decode<<<dim3(29), dim3(256), 0, stream>>>(keys, res_l, idxbuf, out_res, out_idx);
    k_cmap<<<dim3(B_ * N_), dim3(256), 0, stream>>>(q, p, idxbuf,
        bns_g + l * D_, bns_b + l * D_, bns_m + l * D_, bns_v + l * D_, cmap);
    k_fusion<<<dim3(B_ * D_ / 4), dim3(256), 0, stream>>>(cmap, gfeat);
    k_fc<<<dim3(B_), dim3(256), 0, stream>>>(gfeat,
        g1_w + (size_t)l * H_ * D_, gbn1_g + l * H_, gbn1_b + l * H_, gbn1_m + l * H_, gbn1_v + l * H_,
        g2_w + (size_t)l * MID_ * H_, gbn2_g + l * MID_, gbn2_b + l * MID_, gbn2_m + l * MID_, gbn2_v + l * MID_,
        g3_w + (size_t)l * 2 * MID_, out_gl, out_g2c);
    k_prepw<<<dim3(9344), dim3(256), 0, stream>>>(
        lc1_w + (size_t)l * H_ * D_ * 9, lt1_w + (size_t)l * H_ * H_ * 4,
        lc2_w + (size_t)l * MID_ * H_ * 9, lt2_w + (size_t)l * MID_ * MID_ * 4,
        wt1, wtT1, wt2, wtT2);
    k_l2cinit<<<dim3(29, B_), dim3(256), 0, stream>>>(lt2_b + l * MID_,
        lc3_w + (size_t)l * 2 * MID_, lc3_b + l * 2, l2c_l);
    k_conv3x3<15, 768, 256><<<dim3(4, 4, B_), dim3(256), 0, stream>>>(cmap, wt1,
        lbn1_g + l * H_, lbn1_b + l * H_, lbn1_m + l * H_, lbn1_v + l * H_, x1);
    k_convT<15, 256><<<dim3(4, 16, B_), dim3(256), 0, stream>>>(x1, wtT1, lt1_b + l * H_, y1);
    k_conv3x3<30, 256, 128><<<dim3(15, 2, B_), dim3(256), 0, stream>>>(y1, wt2,
        lbn2_g + l * MID_, lbn2_b + l * MID_, lbn2_m + l * MID_, lbn2_v + l * MID_, x2);
    k_convT_fuse<<<dim3(15, 8, B_), dim3(256), 0, stream>>>(x2, wtT2,
        lc3_w + (size_t)l * 2 * MID_, l2c_l);
  }

  // ---------- phase B: finals (fully overwrite l2c/ls chunks incl. scratch) ----------
  for (int l = 0; l < L_; ++l) {
    float* out_ev = ob + OFF_EV + (size_t)l * B_ * N_;
    float* out_pl = ob + OFF_PL + (size_t)l * B_ * N_;
    float* out_l2c = ob + OFF_L2C + (size_t)l * B_ * 2 * 57600;
    float* out_ls = ob + OFF_LS + (size_t)l * B_ * 2 * 57600;
    float* res_l = residual + (size_t)l * B_ * N_;
    float* l2c_l = l2c + (size_t)l * B_ * 7200;
    k_patch<<<dim3(B_), dim3(256), 0, stream>>>(l2c_l, res_l, out_ev, out_pl);
    k_up<<<dim3(225, B_), dim3(256), 0, stream>>>(l2c_l, out_l2c, out_ls);
  }
}

// Round 7
// 1747.747 us; speedup vs baseline: 1.7347x; 1.7347x over previous
//
#include <hip/hip_runtime.h>
#include <hip/hip_bf16.h>
#include <math.h>

typedef unsigned long long u64;
typedef __hip_bfloat16 bf16;
typedef __attribute__((ext_vector_type(8))) short bf16x8;
typedef __attribute__((ext_vector_type(4))) float f32x4;

#define L_ 2
#define B_ 32
#define N_ 225
#define M_ 1800
#define D_ 768
#define H_ 256
#define MID_ 128
#define EPS_ 1e-5f

__device__ __forceinline__ u64 enc_key(float v, int idx) {
  unsigned u = __float_as_uint(v);
  u = (u & 0x80000000u) ? ~u : (u | 0x80000000u);
  return ((u64)u << 32) | (u64)(0x7FFFFFFFu - (unsigned)idx);
}

// ---------------- norms ----------------
__global__ __launch_bounds__(256) void k_norms(const float* __restrict__ q,
                                               const float* __restrict__ p,
                                               float* __restrict__ qinv,
                                               float* __restrict__ pinv) {
  int row = blockIdx.x;
  const float* src;
  float* dst;
  if (row < B_ * N_) {
    src = q + (size_t)row * D_;
    dst = qinv + row;
  } else {
    int r = row - B_ * N_;
    src = p + (size_t)r * D_;
    dst = pinv + r;
  }
  float s = 0.f;
  for (int i = threadIdx.x; i < D_; i += 256) {
    float v = src[i];
    s = fmaf(v, v, s);
  }
  __shared__ float red[256];
  red[threadIdx.x] = s;
  __syncthreads();
  for (int off = 128; off > 0; off >>= 1) {
    if (threadIdx.x < off) red[threadIdx.x] += red[threadIdx.x + off];
    __syncthreads();
  }
  if (threadIdx.x == 0) {
    float n = sqrtf(red[0]);
    n = fmaxf(n, 1e-12f);
    *dst = 1.0f / n;
  }
}

__global__ void k_init(u64* __restrict__ keys) {
  int i = blockIdx.x * 256 + threadIdx.x;
  if (i < B_ * N_) keys[i] = 0ULL;
}

// ---------------- cosine sim + argmax (normalize-first, f32) ----------------
__global__ __launch_bounds__(256) void k_sim(const float* __restrict__ q,
                                             const float* __restrict__ p,
                                             const float* __restrict__ qinv,
                                             const float* __restrict__ pinv,
                                             u64* __restrict__ keys) {
  const int b = blockIdx.z;
  const int n0 = blockIdx.x * 64;
  const int m0 = blockIdx.y * 64;
  __shared__ float As[32][68];
  __shared__ float Bs[32][68];
  __shared__ u64 red[64][17];
  float acc[4][4] = {};
  const int t = threadIdx.x;
  const int tn = t >> 4, tm = t & 15;
  const int lr = t >> 3;
  const int lc = (t & 7) << 2;
  const float* qb = q + (size_t)b * N_ * D_;
  const float* pb = p + (size_t)b * M_ * D_;
  float qs[2], ps[2];
#pragma unroll
  for (int rep = 0; rep < 2; ++rep) {
    int n = n0 + lr + rep * 32;
    qs[rep] = (n < N_) ? qinv[(size_t)b * N_ + n] : 0.f;
    int m = m0 + lr + rep * 32;
    ps[rep] = (m < M_) ? pinv[(size_t)b * M_ + m] : 0.f;
  }

  for (int k0 = 0; k0 < D_; k0 += 32) {
#pragma unroll
    for (int rep = 0; rep < 2; ++rep) {
      int r = lr + rep * 32;
      float4 av = make_float4(0.f, 0.f, 0.f, 0.f);
      int n = n0 + r;
      if (n < N_) av = *(const float4*)(qb + (size_t)n * D_ + k0 + lc);
      As[lc + 0][r] = av.x * qs[rep]; As[lc + 1][r] = av.y * qs[rep];
      As[lc + 2][r] = av.z * qs[rep]; As[lc + 3][r] = av.w * qs[rep];
      float4 bv = make_float4(0.f, 0.f, 0.f, 0.f);
      int m = m0 + r;
      if (m < M_) bv = *(const float4*)(pb + (size_t)m * D_ + k0 + lc);
      Bs[lc + 0][r] = bv.x * ps[rep]; Bs[lc + 1][r] = bv.y * ps[rep];
      Bs[lc + 2][r] = bv.z * ps[rep]; Bs[lc + 3][r] = bv.w * ps[rep];
    }
    __syncthreads();
#pragma unroll
    for (int kk = 0; kk < 32; ++kk) {
      const float4 a = *(const float4*)&As[kk][tn << 2];
      const float4 w = *(const float4*)&Bs[kk][tm << 2];
      acc[0][0] = fmaf(a.x, w.x, acc[0][0]);
      acc[0][1] = fmaf(a.x, w.y, acc[0][1]);
      acc[0][2] = fmaf(a.x, w.z, acc[0][2]);
      acc[0][3] = fmaf(a.x, w.w, acc[0][3]);
      acc[1][0] = fmaf(a.y, w.x, acc[1][0]);
      acc[1][1] = fmaf(a.y, w.y, acc[1][1]);
      acc[1][2] = fmaf(a.y, w.z, acc[1][2]);
      acc[1][3] = fmaf(a.y, w.w, acc[1][3]);
      acc[2][0] = fmaf(a.z, w.x, acc[2][0]);
      acc[2][1] = fmaf(a.z, w.y, acc[2][1]);
      acc[2][2] = fmaf(a.z, w.z, acc[2][2]);
      acc[2][3] = fmaf(a.z, w.w, acc[2][3]);
      acc[3][0] = fmaf(a.w, w.x, acc[3][0]);
      acc[3][1] = fmaf(a.w, w.y, acc[3][1]);
      acc[3][2] = fmaf(a.w, w.z, acc[3][2]);
      acc[3][3] = fmaf(a.w, w.w, acc[3][3]);
    }
    __syncthreads();
  }
  const int mbase = m0 + (tm << 2);
#pragma unroll
  for (int i = 0; i < 4; ++i) {
    u64 bk = 0ULL;
#pragma unroll
    for (int j = 0; j < 4; ++j) {
      int m = mbase + j;
      if (m < M_) {
        u64 k = enc_key(acc[i][j], m);
        if (k > bk) bk = k;
      }
    }
    red[(tn << 2) + i][tm] = bk;
  }
  __syncthreads();
  if (t < 64) {
    u64 bk = 0ULL;
#pragma unroll
    for (int j = 0; j < 16; ++j) {
      u64 k = red[t][j];
      if (k > bk) bk = k;
    }
    int n = n0 + t;
    if (n < N_) atomicMax(&keys[(size_t)b * N_ + n], bk);
  }
}

__global__ void k_decode(const u64* __restrict__ keys, float* __restrict__ residual,
                         int* __restrict__ idxbuf, float* __restrict__ out_res,
                         float* __restrict__ out_idx) {
  int i = blockIdx.x * 256 + threadIdx.x;
  if (i >= B_ * N_) return;
  u64 k = keys[i];
  unsigned u = (unsigned)(k >> 32);
  unsigned bits = (u & 0x80000000u) ? (u & 0x7FFFFFFFu) : ~u;
  float v = __uint_as_float(bits);
  int idx = (int)(0x7FFFFFFFu - (unsigned)(k & 0xFFFFFFFFu));
  if (idx < 0) idx = 0;
  if (idx >= M_) idx = M_ - 1;
  float r = 1.0f - v;
  if (r != r) r = 0.f;
  residual[i] = r;
  idxbuf[i] = idx;
  out_res[i] = r;
  out_idx[i] = (float)idx;
}

// ---------------- ctx -> BN -> cmap (bf16 scratch, [B*N][D]) ----------------
__global__ __launch_bounds__(256) void k_cmap(const float* __restrict__ q,
    const float* __restrict__ p, const int* __restrict__ idxbuf,
    const float* __restrict__ g, const float* __restrict__ bb,
    const float* __restrict__ bm, const float* __restrict__ bv,
    bf16* __restrict__ cmap) {
  int bn = blockIdx.x;
  int b = bn / N_;
  int id = idxbuf[bn];
  if (id < 0) id = 0;
  if (id >= M_) id = M_ - 1;
  const float* qr = q + (size_t)bn * D_;
  const float* pr = p + ((size_t)b * M_ + id) * D_;
  for (int d = threadIdx.x; d < D_; d += 256) {
    float qv = qr[d], pv = pr[d];
    float c = qv + fabsf(qv - pv);
    float val = (c - bm[d]) * (g[d] * rsqrtf(bv[d] + EPS_)) + bb[d];
    cmap[(size_t)bn * D_ + d] = __float2bfloat16(val);
  }
}

// ---------------- weight reshapes to bf16 [cout][k] (MFMA B-staging layout) ----------------
__global__ void k_prepw(const float* __restrict__ lc1, const float* __restrict__ lt1,
                        const float* __restrict__ lc2, const float* __restrict__ lt2,
                        bf16* __restrict__ wt1, bf16* __restrict__ wtT1,
                        bf16* __restrict__ wt2, bf16* __restrict__ wtT2) {
  int i = blockIdx.x * 256 + threadIdx.x;
  const int n1 = 9 * D_ * H_;      // 1769472 : wt1 [co:256][tap*768+d]
  const int n2 = 4 * H_ * H_;      // 262144  : wtT1 [ij][co:256][ci:256]
  const int n3 = 9 * H_ * MID_;    // 294912  : wt2 [co:128][tap*256+ci]
  const int n4 = 4 * MID_ * MID_;  // 65536   : wtT2 [ij][co:128][ci:128]
  if (i < n1) {
    int co = i / 6912;
    int rem = i % 6912;
    int tap = rem / 768;
    int d = rem % 768;
    wt1[i] = __float2bfloat16(lc1[((size_t)co * D_ + d) * 9 + tap]);
  } else if (i < n1 + n2) {
    int j = i - n1;
    int ij = j >> 16;
    int co = (j >> 8) & 255;
    int ci = j & 255;
    wtT1[j] = __float2bfloat16(lt1[((size_t)ci * H_ + co) * 4 + ij]);
  } else if (i < n1 + n2 + n3) {
    int j = i - n1 - n2;
    int co = j / 2304;
    int rem = j % 2304;
    int tap = rem >> 8;
    int ci = rem & 255;
    wt2[j] = __float2bfloat16(lc2[((size_t)co * H_ + ci) * 9 + tap]);
  } else if (i < n1 + n2 + n3 + n4) {
    int j = i - n1 - n2 - n3;
    int ij = j >> 14;
    int co = (j >> 7) & 127;
    int ci = j & 127;
    wtT2[j] = __float2bfloat16(lt2[((size_t)ci * MID_ + co) * 4 + ij]);
  }
}

// ================= MFMA conv kernels =================
// Block: 64 (spatial) x 64 (cout) tile, 4 waves in 2x2, each wave 32x32 via
// 2x2 mfma_f32_16x16x32_bf16. Double-buffered LDS, one barrier per K-step.
// Fragment layout (m89-verified): A/B lane l -> row/col l&15, k (l>>4)*8+e;
// D lane l, reg r -> row (l>>4)*4+r, col l&15.

template <int SHW, int CIN, int COUT>
__global__ __launch_bounds__(256) void k_conv3x3_mfma(
    const bf16* __restrict__ in, const bf16* __restrict__ wt,
    const float* __restrict__ bg, const float* __restrict__ bbeta,
    const float* __restrict__ bm, const float* __restrict__ bv,
    bf16* __restrict__ outp) {
  constexpr int S = SHW * SHW;
  constexpr int K = 9 * CIN;
  constexpr int NS = K / 32;
  constexpr int CS = CIN / 32;
  const int b = blockIdx.z;
  const int s0 = blockIdx.x * 64;
  const int c0 = blockIdx.y * 64;
  __shared__ __align__(16) short As[2][64][40];
  __shared__ __align__(16) short Bs[2][64][40];
  const int t = threadIdx.x;
  const int lane = t & 63;
  const int wm = (t >> 7) & 1;
  const int wn = (t >> 6) & 1;
  const int srow = t >> 2;
  const int sch = (t & 3) * 8;
  const int s_sp = s0 + srow;
  const int sy0 = s_sp / SHW, sx0 = s_sp % SHW;
  const bf16* inb = in + (size_t)b * S * CIN;
  const bf16* wrow = wt + (size_t)(c0 + srow) * K;
  const int lr = lane & 15;
  const int lk = (lane >> 4) * 8;

  f32x4 acc00 = {0.f, 0.f, 0.f, 0.f}, acc01 = {0.f, 0.f, 0.f, 0.f};
  f32x4 acc10 = {0.f, 0.f, 0.f, 0.f}, acc11 = {0.f, 0.f, 0.f, 0.f};

  auto loadA = [&](int kt) -> bf16x8 {
    int tap = kt / CS;
    int c00 = (kt % CS) * 32;
    int dy = tap / 3 - 1, dx = tap % 3 - 1;
    int sy = sy0 + dy, sx = sx0 + dx;
    bf16x8 av = {0, 0, 0, 0, 0, 0, 0, 0};
    if (s_sp < S && sy >= 0 && sy < SHW && sx >= 0 && sx < SHW)
      av = *(const bf16x8*)(inb + (size_t)(sy * SHW + sx) * CIN + c00 + sch);
    return av;
  };

  // prologue: stage step 0 into buffer 0
  {
    bf16x8 av = loadA(0);
    bf16x8 wv = *(const bf16x8*)(wrow + sch);
    *(bf16x8*)&As[0][srow][sch] = av;
    *(bf16x8*)&Bs[0][srow][sch] = wv;
  }
  __syncthreads();
  int cur = 0;
  for (int kt = 0; kt < NS; ++kt) {
    bf16x8 avn, wvn;
    if (kt + 1 < NS) {
      avn = loadA(kt + 1);
      wvn = *(const bf16x8*)(wrow + (kt + 1) * 32 + sch);
    }
    bf16x8 a0 = *(const bf16x8*)&As[cur][wm * 32 + lr][lk];
    bf16x8 a1 = *(const bf16x8*)&As[cur][wm * 32 + 16 + lr][lk];
    bf16x8 b0 = *(const bf16x8*)&Bs[cur][wn * 32 + lr][lk];
    bf16x8 b1 = *(const bf16x8*)&Bs[cur][wn * 32 + 16 + lr][lk];
    acc00 = __builtin_amdgcn_mfma_f32_16x16x32_bf16(a0, b0, acc00, 0, 0, 0);
    acc01 = __builtin_amdgcn_mfma_f32_16x16x32_bf16(a0, b1, acc01, 0, 0, 0);
    acc10 = __builtin_amdgcn_mfma_f32_16x16x32_bf16(a1, b0, acc10, 0, 0, 0);
    acc11 = __builtin_amdgcn_mfma_f32_16x16x32_bf16(a1, b1, acc11, 0, 0, 0);
    if (kt + 1 < NS) {
      *(bf16x8*)&As[cur ^ 1][srow][sch] = avn;
      *(bf16x8*)&Bs[cur ^ 1][srow][sch] = wvn;
    }
    __syncthreads();
    cur ^= 1;
  }

  auto emit = [&](const f32x4& a, int mi, int ni) {
    int c = c0 + wn * 32 + ni * 16 + lr;
    float sg = bg[c] * rsqrtf(bv[c] + EPS_);
    float sh = bbeta[c] - bm[c] * sg;
#pragma unroll
    for (int r = 0; r < 4; ++r) {
      int s = s0 + wm * 32 + mi * 16 + (lane >> 4) * 4 + r;
      if (s < S)
        outp[((size_t)b * S + s) * COUT + c] =
            __float2bfloat16(fmaxf(fmaf(a[r], sg, sh), 0.f));
    }
  };
  emit(acc00, 0, 0);
  emit(acc01, 0, 1);
  emit(acc10, 1, 0);
  emit(acc11, 1, 1);
}

template <int SHW, int C>
__global__ __launch_bounds__(256) void k_convT_mfma(
    const bf16* __restrict__ in, const bf16* __restrict__ wt,
    const float* __restrict__ bias, bf16* __restrict__ outp) {
  constexpr int S = SHW * SHW;
  constexpr int NS = C / 32;
  const int b = blockIdx.z;
  const int ij = blockIdx.y & 3;
  const int c0 = (blockIdx.y >> 2) * 64;
  const int s0 = blockIdx.x * 64;
  __shared__ __align__(16) short As[2][64][40];
  __shared__ __align__(16) short Bs[2][64][40];
  const int t = threadIdx.x;
  const int lane = t & 63;
  const int wm = (t >> 7) & 1;
  const int wn = (t >> 6) & 1;
  const int srow = t >> 2;
  const int sch = (t & 3) * 8;
  const int s_sp = s0 + srow;
  const bf16* arow = in + ((size_t)b * S + s_sp) * C;
  const bf16* wrow = wt + (size_t)ij * C * C + (size_t)(c0 + srow) * C;
  const int lr = lane & 15;
  const int lk = (lane >> 4) * 8;

  f32x4 acc00 = {0.f, 0.f, 0.f, 0.f}, acc01 = {0.f, 0.f, 0.f, 0.f};
  f32x4 acc10 = {0.f, 0.f, 0.f, 0.f}, acc11 = {0.f, 0.f, 0.f, 0.f};

  {
    bf16x8 av = {0, 0, 0, 0, 0, 0, 0, 0};
    if (s_sp < S) av = *(const bf16x8*)(arow + sch);
    bf16x8 wv = *(const bf16x8*)(wrow + sch);
    *(bf16x8*)&As[0][srow][sch] = av;
    *(bf16x8*)&Bs[0][srow][sch] = wv;
  }
  __syncthreads();
  int cur = 0;
  for (int kt = 0; kt < NS; ++kt) {
    bf16x8 avn = {0, 0, 0, 0, 0, 0, 0, 0}, wvn;
    if (kt + 1 < NS) {
      if (s_sp < S) avn = *(const bf16x8*)(arow + (kt + 1) * 32 + sch);
      wvn = *(const bf16x8*)(wrow + (kt + 1) * 32 + sch);
    }
    bf16x8 a0 = *(const bf16x8*)&As[cur][wm * 32 + lr][lk];
    bf16x8 a1 = *(const bf16x8*)&As[cur][wm * 32 + 16 + lr][lk];
    bf16x8 b0 = *(const bf16x8*)&Bs[cur][wn * 32 + lr][lk];
    bf16x8 b1 = *(const bf16x8*)&Bs[cur][wn * 32 + 16 + lr][lk];
    acc00 = __builtin_amdgcn_mfma_f32_16x16x32_bf16(a0, b0, acc00, 0, 0, 0);
    acc01 = __builtin_amdgcn_mfma_f32_16x16x32_bf16(a0, b1, acc01, 0, 0, 0);
    acc10 = __builtin_amdgcn_mfma_f32_16x16x32_bf16(a1, b0, acc10, 0, 0, 0);
    acc11 = __builtin_amdgcn_mfma_f32_16x16x32_bf16(a1, b1, acc11, 0, 0, 0);
    if (kt + 1 < NS) {
      *(bf16x8*)&As[cur ^ 1][srow][sch] = avn;
      *(bf16x8*)&Bs[cur ^ 1][srow][sch] = wvn;
    }
    __syncthreads();
    cur ^= 1;
  }

  auto emit = [&](const f32x4& a, int mi, int ni) {
    int c = c0 + wn * 32 + ni * 16 + lr;
    float bj = bias[c];
#pragma unroll
    for (int r = 0; r < 4; ++r) {
      int s = s0 + wm * 32 + mi * 16 + (lane >> 4) * 4 + r;
      if (s < S) {
        int oy = 2 * (s / SHW) + (ij >> 1);
        int ox = 2 * (s % SHW) + (ij & 1);
        outp[((size_t)b * 4 * S + (size_t)oy * (2 * SHW) + ox) * C + c] =
            __float2bfloat16(a[r] + bj);
      }
    }
  };
  emit(acc00, 0, 0);
  emit(acc01, 0, 1);
  emit(acc10, 1, 0);
  emit(acc11, 1, 1);
}

// convT2 (30->60) fused with 1x1 conv -> atomicAdd into f32 l2c
__global__ __launch_bounds__(256) void k_convT_fuse_mfma(
    const bf16* __restrict__ in, const bf16* __restrict__ wt,
    const float* __restrict__ w3, float* __restrict__ l2c) {
  constexpr int SHW = 30, C = 128, S = SHW * SHW;
  constexpr int NS = C / 32;
  const int b = blockIdx.z;
  const int ij = blockIdx.y & 3;
  const int c0 = (blockIdx.y >> 2) * 64;
  const int s0 = blockIdx.x * 64;
  __shared__ __align__(16) short As[2][64][40];
  __shared__ __align__(16) short Bs[2][64][40];
  __shared__ float red0[64][2];
  __shared__ float red1[64][2];
  const int t = threadIdx.x;
  const int lane = t & 63;
  const int wm = (t >> 7) & 1;
  const int wn = (t >> 6) & 1;
  const int srow = t >> 2;
  const int sch = (t & 3) * 8;
  const int s_sp = s0 + srow;
  const bf16* arow = in + ((size_t)b * S + s_sp) * C;
  const bf16* wrow = wt + (size_t)ij * C * C + (size_t)(c0 + srow) * C;
  const int lr = lane & 15;
  const int lk = (lane >> 4) * 8;

  f32x4 acc00 = {0.f, 0.f, 0.f, 0.f}, acc01 = {0.f, 0.f, 0.f, 0.f};
  f32x4 acc10 = {0.f, 0.f, 0.f, 0.f}, acc11 = {0.f, 0.f, 0.f, 0.f};

  {
    bf16x8 av = {0, 0, 0, 0, 0, 0, 0, 0};
    if (s_sp < S) av = *(const bf16x8*)(arow + sch);
    bf16x8 wv = *(const bf16x8*)(wrow + sch);
    *(bf16x8*)&As[0][srow][sch] = av;
    *(bf16x8*)&Bs[0][srow][sch] = wv;
  }
  __syncthreads();
  int cur = 0;
  for (int kt = 0; kt < NS; ++kt) {
    bf16x8 avn = {0, 0, 0, 0, 0, 0, 0, 0}, wvn;
    if (kt + 1 < NS) {
      if (s_sp < S) avn = *(const bf16x8*)(arow + (kt + 1) * 32 + sch);
      wvn = *(const bf16x8*)(wrow + (kt + 1) * 32 + sch);
    }
    bf16x8 a0 = *(const bf16x8*)&As[cur][wm * 32 + lr][lk];
    bf16x8 a1 = *(const bf16x8*)&As[cur][wm * 32 + 16 + lr][lk];
    bf16x8 b0 = *(const bf16x8*)&Bs[cur][wn * 32 + lr][lk];
    bf16x8 b1 = *(const bf16x8*)&Bs[cur][wn * 32 + 16 + lr][lk];
    acc00 = __builtin_amdgcn_mfma_f32_16x16x32_bf16(a0, b0, acc00, 0, 0, 0);
    acc01 = __builtin_amdgcn_mfma_f32_16x16x32_bf16(a0, b1, acc01, 0, 0, 0);
    acc10 = __builtin_amdgcn_mfma_f32_16x16x32_bf16(a1, b0, acc10, 0, 0, 0);
    acc11 = __builtin_amdgcn_mfma_f32_16x16x32_bf16(a1, b1, acc11, 0, 0, 0);
    if (kt + 1 < NS) {
      *(bf16x8*)&As[cur ^ 1][srow][sch] = avn;
      *(bf16x8*)&Bs[cur ^ 1][srow][sch] = wvn;
    }
    __syncthreads();
    cur ^= 1;
  }

  // 1x1 fold: per thread its 2 columns per ni; reduce 16 lanes -> row partial
  const float w0a = w3[c0 + wn * 32 + lr];
  const float w0b = w3[c0 + wn * 32 + 16 + lr];
  const float w1a = w3[MID_ + c0 + wn * 32 + lr];
  const float w1b = w3[MID_ + c0 + wn * 32 + 16 + lr];
#pragma unroll
  for (int mi = 0; mi < 2; ++mi) {
    f32x4 aa0 = mi ? acc10 : acc00;
    f32x4 aa1 = mi ? acc11 : acc01;
#pragma unroll
    for (int r = 0; r < 4; ++r) {
      float p0 = aa0[r] * w0a + aa1[r] * w0b;
      float p1 = aa0[r] * w1a + aa1[r] * w1b;
      p0 += __shfl_xor(p0, 1); p0 += __shfl_xor(p0, 2);
      p0 += __shfl_xor(p0, 4); p0 += __shfl_xor(p0, 8);
      p1 += __shfl_xor(p1, 1); p1 += __shfl_xor(p1, 2);
      p1 += __shfl_xor(p1, 4); p1 += __shfl_xor(p1, 8);
      if (lr == 0) {
        int rl = wm * 32 + mi * 16 + (lane >> 4) * 4 + r;
        red0[rl][wn] = p0;
        red1[rl][wn] = p1;
      }
    }
  }
  __syncthreads();
  if (t < 64) {
    int s = s0 + t;
    if (s < S) {
      float v0 = red0[t][0] + red0[t][1];
      float v1 = red1[t][0] + red1[t][1];
      int oy = 2 * (s / SHW) + (ij >> 1);
      int ox = 2 * (s % SHW) + (ij & 1);
      int opix = oy * 60 + ox;
      atomicAdd(&l2c[(size_t)b * 7200 + opix], v0);
      atomicAdd(&l2c[(size_t)b * 7200 + 3600 + opix], v1);
    }
  }
}

// ---------------- l2c init: b3 + lt2_b folded through 1x1 ----------------
__global__ void k_l2cinit(const float* __restrict__ lt2b, const float* __restrict__ w3,
                          const float* __restrict__ b3, float* __restrict__ l2c) {
  __shared__ float ini[2];
  int t = threadIdx.x;
  if (t < 2) {
    float s = b3[t];
    for (int ci = 0; ci < MID_; ++ci) s = fmaf(lt2b[ci], w3[t * MID_ + ci], s);
    ini[t] = s;
  }
  __syncthreads();
  int i = blockIdx.x * 256 + t;
  if (i < 7200) l2c[(size_t)blockIdx.y * 7200 + i] = ini[i / 3600];
}

// ---------------- patch head: exact resize(resize(60->240)->15) + evidence ----------------
__global__ __launch_bounds__(256) void k_patch(const float* __restrict__ l2c,
    const float* __restrict__ residual, float* __restrict__ out_ev,
    float* __restrict__ out_pl) {
  const int b = blockIdx.x;
  __shared__ float sm0[3600];
  __shared__ float sm1[3600];
  for (int i = threadIdx.x; i < 3600; i += 256) {
    sm0[i] = l2c[(size_t)b * 7200 + i];
    sm1[i] = l2c[(size_t)b * 7200 + 3600 + i];
  }
  __syncthreads();
  const int t = threadIdx.x;
  if (t >= 225) return;
  const int py = t / 15, px = t % 15;
  const float cy = 16.f * py + 7.5f;
  const float cx = 16.f * px + 7.5f;
  const int ky_lo = max(0, 16 * py - 8), ky_hi = min(239, 16 * py + 23);
  const int kx_lo = max(0, 16 * px - 8), kx_hi = min(239, 16 * px + 23);
  float acc0 = 0.f, acc1 = 0.f, wsum = 0.f;
  for (int ky = ky_lo; ky <= ky_hi; ++ky) {
    float wy = 1.f - fabsf((float)ky - cy) * 0.0625f;
    float c60y = 0.25f * ky - 0.375f;
    int jy = (int)floorf(c60y);
    float fy = c60y - (float)jy;
    int jy0 = max(jy, 0), jy1 = min(jy + 1, 59);
    for (int kx = kx_lo; kx <= kx_hi; ++kx) {
      float wx = 1.f - fabsf((float)kx - cx) * 0.0625f;
      float w = wy * wx;
      float c60x = 0.25f * kx - 0.375f;
      int jx = (int)floorf(c60x);
      float fx = c60x - (float)jx;
      int jx0 = max(jx, 0), jx1 = min(jx + 1, 59);
      float v0 = (1.f - fy) * ((1.f - fx) * sm0[jy0 * 60 + jx0] + fx * sm0[jy0 * 60 + jx1])
               + fy * ((1.f - fx) * sm0[jy1 * 60 + jx0] + fx * sm0[jy1 * 60 + jx1]);
      float v1 = (1.f - fy) * ((1.f - fx) * sm1[jy0 * 60 + jx0] + fx * sm1[jy0 * 60 + jx1])
               + fy * ((1.f - fx) * sm1[jy1 * 60 + jx0] + fx * sm1[jy1 * 60 + jx1]);
      acc0 = fmaf(w, v0, acc0);
      acc1 = fmaf(w, v1, acc1);
      wsum += w;
    }
  }
  float p0 = acc0 / wsum, p1 = acc1 / wsum;
  float logit = p1 - p0;
  float score1 = 1.0f / (1.0f + expf(p0 - p1));
  float ev = 0.5f * residual[b * N_ + t] + 0.5f * score1;
  out_pl[b * N_ + t] = logit;
  out_ev[b * N_ + t] = ev;
}

// ---------------- upsample 60->240 bilinear: write local2c AND softmax (f32) ----------------
__global__ __launch_bounds__(256) void k_up(const float* __restrict__ l2c,
                                            float* __restrict__ out_l2c,
                                            float* __restrict__ out_ls) {
  const int b = blockIdx.y;
  const int pix = blockIdx.x * 256 + threadIdx.x;  // 57600
  const int y = pix / 240, x = pix % 240;
  float sy = 0.25f * y - 0.375f;
  int ky = (int)floorf(sy);
  float fy = sy - (float)ky;
  float sx = 0.25f * x - 0.375f;
  int kx = (int)floorf(sx);
  float fx = sx - (float)kx;
  int ky0 = max(ky, 0), ky1 = min(ky + 1, 59);
  int kx0 = max(kx, 0), kx1 = min(kx + 1, 59);
  float v[2];
#pragma unroll
  for (int c = 0; c < 2; ++c) {
    const float* base = l2c + ((size_t)b * 2 + c) * 3600;
    float top = (1.f - fx) * base[ky0 * 60 + kx0] + fx * base[ky0 * 60 + kx1];
    float bot = (1.f - fx) * base[ky1 * 60 + kx0] + fx * base[ky1 * 60 + kx1];
    v[c] = (1.f - fy) * top + fy * bot;
  }
  float s1 = 1.f / (1.f + expf(v[0] - v[1]));
  float s0 = 1.f / (1.f + expf(v[1] - v[0]));
  size_t o0 = ((size_t)b * 2 + 0) * 57600 + pix;
  size_t o1 = ((size_t)b * 2 + 1) * 57600 + pix;
  out_l2c[o0] = v[0];
  out_l2c[o1] = v[1];
  out_ls[o0] = s0;
  out_ls[o1] = s1;
}

// ---------------- fusion stats (strided read from cmap [B*N][D]) ----------------
__global__ __launch_bounds__(256) void k_fusion(const bf16* __restrict__ cmap,
                                                float* __restrict__ gfeat) {
  int wid = ((blockIdx.x * 256 + threadIdx.x) >> 6);
  int lane = threadIdx.x & 63;
  if (wid >= B_ * D_) return;
  int b = wid / D_, d = wid % D_;
  const bf16* base = cmap + (size_t)b * N_ * D_ + d;
  float v[4];
  bool alive[4];
  float sum = 0.f;
#pragma unroll
  for (int r = 0; r < 4; ++r) {
    int n = lane + r * 64;
    bool ok = (n < N_);
    v[r] = ok ? __bfloat162float(base[(size_t)n * D_]) : -INFINITY;
    alive[r] = ok;
    if (ok) sum += v[r];
  }
  for (int o = 32; o > 0; o >>= 1) sum += __shfl_xor(sum, o);
  float topsum = 0.f;
  for (int it = 0; it < 10; ++it) {
    float lm = -INFINITY;
    int ls = -1;
#pragma unroll
    for (int r = 0; r < 4; ++r)
      if (alive[r] && v[r] > lm) { lm = v[r]; ls = r; }
    float wm = lm;
    for (int o = 32; o > 0; o >>= 1) wm = fmaxf(wm, __shfl_xor(wm, o));
    topsum += wm;
    u64 ball = __ballot(lm == wm);
    int owner = __ffsll((long long)ball) - 1;
    if (lane == owner && ls >= 0) alive[ls] = false;
  }
  if (lane == 0) gfeat[wid] = 0.5f * (sum / 225.0f + topsum * 0.1f);
}

// ---------------- fused FC head ----------------
__global__ __launch_bounds__(256) void k_fc(const float* __restrict__ gfeat,
    const float* __restrict__ g1w, const float* __restrict__ bg1,
    const float* __restrict__ bb1, const float* __restrict__ bm1,
    const float* __restrict__ bv1, const float* __restrict__ g2w,
    const float* __restrict__ bg2, const float* __restrict__ bb2,
    const float* __restrict__ bm2, const float* __restrict__ bv2,
    const float* __restrict__ g3w, float* __restrict__ out_gl,
    float* __restrict__ out_g2c) {
  __shared__ float gf[D_];
  __shared__ float h1s[H_];
  __shared__ float h2s[MID_];
  __shared__ float g2cs[2];
  const int b = blockIdx.x;
  const int t = threadIdx.x;
  for (int i = t; i < D_; i += 256) gf[i] = gfeat[b * D_ + i];
  __syncthreads();
  {
    float a = 0.f;
    const float* w = g1w + (size_t)t * D_;
    for (int d = 0; d < D_; ++d) a = fmaf(gf[d], w[d], a);
    float s = bg1[t] * rsqrtf(bv1[t] + EPS_);
    h1s[t] = fmaxf((a - bm1[t]) * s + bb1[t], 0.f);
  }
  __syncthreads();
  if (t < MID_) {
    float a = 0.f;
    const float* w = g2w + (size_t)t * H_;
    for (int k = 0; k < H_; ++k) a = fmaf(h1s[k], w[k], a);
    float s = bg2[t] * rsqrtf(bv2[t] + EPS_);
    h2s[t] = fmaxf((a - bm2[t]) * s + bb2[t], 0.f);
  }
  __syncthreads();
  if (t < 2) {
    float a = 0.f;
    const float* w = g3w + (size_t)t * MID_;
    for (int k = 0; k < MID_; ++k) a = fmaf(h2s[k], w[k], a);
    g2cs[t] = a;
    out_g2c[b * 2 + t] = a;
  }
  __syncthreads();
  if (t == 0) out_gl[b] = g2cs[1] - g2cs[0];
}

// ================= host =================
extern "C" void kernel_launch(void* const* d_in, const int* in_sizes, int n_in,
                              void* d_out, int out_size, void* d_ws, size_t ws_size,
                              hipStream_t stream) {
  (void)in_sizes; (void)n_in; (void)out_size; (void)ws_size;
  const float* query = (const float*)d_in[0];
  const float* prompt = (const float*)d_in[1];
  const float* bns_g = (const float*)d_in[2];
  const float* bns_b = (const float*)d_in[3];
  const float* bns_m = (const float*)d_in[4];
  const float* bns_v = (const float*)d_in[5];
  const float* lc1_w = (const float*)d_in[6];
  const float* lbn1_g = (const float*)d_in[7];
  const float* lbn1_b = (const float*)d_in[8];
  const float* lbn1_m = (const float*)d_in[9];
  const float* lbn1_v = (const float*)d_in[10];
  const float* lt1_w = (const float*)d_in[11];
  const float* lt1_b = (const float*)d_in[12];
  const float* lc2_w = (const float*)d_in[13];
  const float* lbn2_g = (const float*)d_in[14];
  const float* lbn2_b = (const float*)d_in[15];
  const float* lbn2_m = (const float*)d_in[16];
  const float* lbn2_v = (const float*)d_in[17];
  const float* lt2_w = (const float*)d_in[18];
  const float* lt2_b = (const float*)d_in[19];
  const float* lc3_w = (const float*)d_in[20];
  const float* lc3_b = (const float*)d_in[21];
  const float* g1_w = (const float*)d_in[22];
  const float* gbn1_g = (const float*)d_in[23];
  const float* gbn1_b = (const float*)d_in[24];
  const float* gbn1_m = (const float*)d_in[25];
  const float* gbn1_v = (const float*)d_in[26];
  const float* g2_w = (const float*)d_in[27];
  const float* gbn2_g = (const float*)d_in[28];
  const float* gbn2_b = (const float*)d_in[29];
  const float* gbn2_m = (const float*)d_in[30];
  const float* gbn2_v = (const float*)d_in[31];
  const float* g3_w = (const float*)d_in[32];

  float* ob = (float*)d_out;  // output is float32
  char* ob_c = (char*)d_out;
  char* ws = (char*)d_ws;
  // --- small workspace (~6.8 MB total) ---
  u64* keys = (u64*)(ws + 0);                    // 57,600 B
  float* qinv = (float*)(ws + 57600);            // 28,800
  float* pinv = (float*)(ws + 86400);            // 230,400
  float* residual = (float*)(ws + 316800);       // 57,600
  int* idxbuf = (int*)(ws + 374400);             // 28,800
  float* gfeat = (float*)(ws + 403200);          // 98,304
  float* l2c = (float*)(ws + 501504);            // 1,843,200
  bf16* wt1 = (bf16*)(ws + 2344704);             // 3,538,944
  bf16* wtT1 = (bf16*)(ws + 5883648);            // 524,288
  bf16* wt2 = (bf16*)(ws + 6407936);             // 589,824
  bf16* wtT2 = (bf16*)(ws + 6997760);            // 131,072 -> end 7,128,832

  // output offsets in f32 elements (return order: ev, pl, gl, g2c, l2c, ls, res, idx)
  const size_t OFF_EV = 0;
  const size_t OFF_PL = 14400;
  const size_t OFF_GL = 28800;
  const size_t OFF_G2C = 28864;
  const size_t OFF_L2C = 28992;
  const size_t OFF_LS = 7401792;
  const size_t OFF_RES = 14774592;
  const size_t OFF_IDX = 14788992;

  // bf16 conv scratch packed into the BYTE range of the l2c/ls chunks
  // (bytes [115968, 59098368)); fully overwritten by k_up in phase B
  bf16* cmap = (bf16*)(ob_c + 115968);     // 11,059,200 B -> 11,175,168
  bf16* x1 = (bf16*)(ob_c + 11175168);     //  3,686,400 B -> 14,861,568
  bf16* y1 = (bf16*)(ob_c + 14861568);     // 14,745,600 B -> 29,607,168
  bf16* x2 = (bf16*)(ob_c + 29607168);     //  7,372,800 B -> 36,979,968 (< 59,098,368 ok)

  // ---------- phase A ----------
  for (int l = 0; l < L_; ++l) {
    const float* q = query + (size_t)l * B_ * N_ * D_;
    const float* p = prompt + (size_t)l * B_ * M_ * D_;
    float* out_gl = ob + OFF_GL + (size_t)l * B_;
    float* out_g2c = ob + OFF_G2C + (size_t)l * B_ * 2;
    float* out_res = ob + OFF_RES + (size_t)l * B_ * N_;
    float* out_idx = ob + OFF_IDX + (size_t)l * B_ * N_;
    float* res_l = residual + (size_t)l * B_ * N_;
    float* l2c_l = l2c + (size_t)l * B_ * 7200;

    k_norms<<<dim3(B_ * (N_ + M_)), dim3(256), 0, stream>>>(q, p, qinv, pinv);
    k_init<<<dim3(29), dim3(256), 0, stream>>>(keys);
    k_sim<<<dim3(4, 29, B_), dim3(256), 0, stream>>>(q, p, qinv, pinv, keys);
    k_decode<<<dim3(29), dim3(256), 0, stream>>>(keys, res_l, idxbuf, out_res, out_idx);
    k_cmap<<<dim3(B_ * N_), dim3(256), 0, stream>>>(q, p, idxbuf,
        bns_g + l * D_, bns_b + l * D_, bns_m + l * D_, bns_v + l * D_, cmap);
    k_fusion<<<dim3(B_ * D_ / 4), dim3(256), 0, stream>>>(cmap, gfeat);
    k_fc<<<dim3(B_), dim3(256), 0, stream>>>(gfeat,
        g1_w + (size_t)l * H_ * D_, gbn1_g + l * H_, gbn1_b + l * H_, gbn1_m + l * H_, gbn1_v + l * H_,
        g2_w + (size_t)l * MID_ * H_, gbn2_g + l * MID_, gbn2_b + l * MID_, gbn2_m + l * MID_, gbn2_v + l * MID_,
        g3_w + (size_t)l * 2 * MID_, out_gl, out_g2c);
    k_prepw<<<dim3(9344), dim3(256), 0, stream>>>(
        lc1_w + (size_t)l * H_ * D_ * 9, lt1_w + (size_t)l * H_ * H_ * 4,
        lc2_w + (size_t)l * MID_ * H_ * 9, lt2_w + (size_t)l * MID_ * MID_ * 4,
        wt1, wtT1, wt2, wtT2);
    k_l2cinit<<<dim3(29, B_), dim3(256), 0, stream>>>(lt2_b + l * MID_,
        lc3_w + (size_t)l * 2 * MID_, lc3_b + l * 2, l2c_l);
    k_conv3x3_mfma<15, 768, 256><<<dim3(4, 4, B_), dim3(256), 0, stream>>>(cmap, wt1,
        lbn1_g + l * H_, lbn1_b + l * H_, lbn1_m + l * H_, lbn1_v + l * H_, x1);
    k_convT_mfma<15, 256><<<dim3(4, 16, B_), dim3(256), 0, stream>>>(x1, wtT1,
        lt1_b + l * H_, y1);
    k_conv3x3_mfma<30, 256, 128><<<dim3(15, 2, B_), dim3(256), 0, stream>>>(y1, wt2,
        lbn2_g + l * MID_, lbn2_b + l * MID_, lbn2_m + l * MID_, lbn2_v + l * MID_, x2);
    k_convT_fuse_mfma<<<dim3(15, 8, B_), dim3(256), 0, stream>>>(x2, wtT2,
        lc3_w + (size_t)l * 2 * MID_, l2c_l);
  }

  // ---------- phase B: finals (fully overwrite l2c/ls chunks incl. scratch) ----------
  for (int l = 0; l < L_; ++l) {
    float* out_ev = ob + OFF_EV + (size_t)l * B_ * N_;
    float* out_pl = ob + OFF_PL + (size_t)l * B_ * N_;
    float* out_l2c = ob + OFF_L2C + (size_t)l * B_ * 2 * 57600;
    float* out_ls = ob + OFF_LS + (size_t)l * B_ * 2 * 57600;
    float* res_l = residual + (size_t)l * B_ * N_;
    float* l2c_l = l2c + (size_t)l * B_ * 7200;
    k_patch<<<dim3(B_), dim3(256), 0, stream>>>(l2c_l, res_l, out_ev, out_pl);
    k_up<<<dim3(225, B_), dim3(256), 0, stream>>>(l2c_l, out_l2c, out_ls);
  }
}